// Round 1
// baseline (1158.885 us; speedup 1.0000x reference)
//
#include <hip/hip_runtime.h>
#include <hip/hip_bf16.h>

#define NN   3072
#define NE   147456
#define NP   100000
#define HID  256
#define INCH 128
#define CATK 144

typedef __attribute__((ext_vector_type(4))) float    f32x4;
typedef __attribute__((ext_vector_type(8))) _Float16 f16x8;

// ---------------- async global->LDS (16B) ----------------
__device__ __forceinline__ void gload16(const void* g, void* l) {
  __builtin_amdgcn_global_load_lds((const __attribute__((address_space(1))) void*)g,
                                   (__attribute__((address_space(3))) void*)l, 16, 0, 0);
}

// ---------------- adjacency build ----------------
__global__ void scatter_adj_kernel(const int* __restrict__ ei, float* __restrict__ adj) {
  int e = blockIdx.x * 256 + threadIdx.x;
  if (e < NE) {
    int s = ei[e], t = ei[NE + e];
    atomicAdd(&adj[(size_t)s * NN + t], 1.0f);
  }
}

// row-normalize: rw[i][j] = adj[i][j] / max(rowsum, 1)   (fp16 out)
__global__ void rownorm_kernel(const float* __restrict__ adj, _Float16* __restrict__ rw) {
  int row = blockIdx.x, tid = threadIdx.x;
  const float* ap = adj + (size_t)row * NN;
  float s = 0.f;
  for (int j = tid; j < NN; j += 256) s += ap[j];
  for (int d = 32; d; d >>= 1) s += __shfl_xor(s, d);
  __shared__ float w4[4];
  if ((tid & 63) == 0) w4[tid >> 6] = s;
  __syncthreads();
  float inv = 1.f / fmaxf(w4[0] + w4[1] + w4[2] + w4[3], 1.f);
  _Float16* rp = rw + (size_t)row * NN;
  for (int j = tid; j < NN; j += 256) rp[j] = (_Float16)(ap[j] * inv);
}

// ---------------- fp16 64x64-tiled transpose ----------------
__global__ void transpose_f16_kernel(const unsigned short* __restrict__ in,
                                     unsigned short* __restrict__ out) {
  __shared__ unsigned short t[64][65];
  int bx = blockIdx.x, by = blockIdx.y, tid = threadIdx.x;
#pragma unroll
  for (int ii = 0; ii < 16; ii++) {
    int lin = ii * 256 + tid, r = lin >> 6, c = lin & 63;
    t[r][c] = in[(size_t)(by * 64 + r) * NN + bx * 64 + c];
  }
  __syncthreads();
#pragma unroll
  for (int ii = 0; ii < 16; ii++) {
    int lin = ii * 256 + tid, r = lin >> 6, c = lin & 63;
    out[(size_t)(bx * 64 + r) * NN + by * 64 + c] = t[c][r];
  }
}

// ---------------- fp16 MFMA GEMM: C = A * Bt^T  (both row-major [n][n]) ----------------
// 128x128 tile, 4 waves (each 64x64 = 4x4 frags of 16x16), BK=32, global_load_lds staging.
__global__ __launch_bounds__(256) void gemm_f16_nt(const _Float16* __restrict__ A,
                                                   const _Float16* __restrict__ Bt,
                                                   _Float16* __restrict__ C, int n) {
  __shared__ _Float16 As[128 * 32];
  __shared__ _Float16 Bs[128 * 32];
  const int tid = threadIdx.x;
  const int lane = tid & 63, wave = tid >> 6;
  const int wr = wave >> 1, wc = wave & 1;
  const int rowA0 = blockIdx.y * 128, rowB0 = blockIdx.x * 128;
  const int fr = lane & 15;        // m / n index within 16x16 frag
  const int fk = (lane >> 4) * 8;  // k offset (8 contiguous per lane)
  const int ldsoff = tid * 8;      // elements: == (tid>>2)*32 + (tid&3)*8
  const int gr = tid >> 2, gc = (tid & 3) * 8;
  f32x4 acc[4][4] = {};
  const int nkt = n >> 5;
  for (int kt = 0; kt < nkt; ++kt) {
    const int k0 = kt << 5;
    const _Float16* ga = A + (size_t)(rowA0 + gr) * n + k0 + gc;
    const _Float16* gb = Bt + (size_t)(rowB0 + gr) * n + k0 + gc;
    gload16(ga, As + ldsoff);
    gload16(ga + (size_t)64 * n, As + 2048 + ldsoff);
    gload16(gb, Bs + ldsoff);
    gload16(gb + (size_t)64 * n, Bs + 2048 + ldsoff);
    __syncthreads();
    f16x8 af[4], bf[4];
#pragma unroll
    for (int i = 0; i < 4; i++) {
      af[i] = *(const f16x8*)(As + (wr * 64 + i * 16 + fr) * 32 + fk);
      bf[i] = *(const f16x8*)(Bs + (wc * 64 + i * 16 + fr) * 32 + fk);
    }
#pragma unroll
    for (int i = 0; i < 4; i++)
#pragma unroll
      for (int j = 0; j < 4; j++)
        acc[i][j] = __builtin_amdgcn_mfma_f32_16x16x32_f16(af[i], bf[j], acc[i][j], 0, 0, 0);
    __syncthreads();
  }
  const int crow0 = rowA0 + wr * 64, ccol0 = rowB0 + wc * 64;
#pragma unroll
  for (int i = 0; i < 4; i++)
#pragma unroll
    for (int j = 0; j < 4; j++)
#pragma unroll
      for (int r = 0; r < 4; r++) {
        int row = crow0 + i * 16 + (lane >> 4) * 4 + r;
        int col = ccol0 + j * 16 + (lane & 15);
        C[(size_t)row * n + col] = (_Float16)acc[i][j][r];
      }
}

// ---------------- diagonals ----------------
__global__ void diag_extract_kernel(const _Float16* __restrict__ M, float* __restrict__ out) {
  int i = blockIdx.x * 256 + threadIdx.x;
  if (i < NN) out[i] = (float)M[(size_t)i * (NN + 1)];
}

// out[i] = sum_j X[i,j] * Yt[i,j]
__global__ void diag_prod_kernel(const _Float16* __restrict__ X, const _Float16* __restrict__ Yt,
                                 float* __restrict__ out) {
  int row = blockIdx.x, tid = threadIdx.x;
  const f16x8* xp = (const f16x8*)(X + (size_t)row * NN);
  const f16x8* yp = (const f16x8*)(Yt + (size_t)row * NN);
  float s = 0.f;
  for (int j = tid; j < NN / 8; j += 256) {
    f16x8 a = xp[j], b = yp[j];
#pragma unroll
    for (int r = 0; r < 8; r++) s += (float)a[r] * (float)b[r];
  }
  for (int d = 32; d; d >>= 1) s += __shfl_xor(s, d);
  __shared__ float w4[4];
  if ((tid & 63) == 0) w4[tid >> 6] = s;
  __syncthreads();
  if (tid == 0) out[row] = w4[0] + w4[1] + w4[2] + w4[3];
}

// pe[i][d] = b[d] + sum_t diags[t][i] * w[t][d]
__global__ void pe_kernel(const float* __restrict__ diags, const float* __restrict__ w,
                          const float* __restrict__ b, float* __restrict__ pe) {
  int idx = blockIdx.x * 256 + threadIdx.x;
  if (idx >= NN * 16) return;
  int i = idx >> 4, d = idx & 15;
  float s = b[d];
#pragma unroll
  for (int t = 0; t < 16; t++) s += diags[t * NN + i] * w[t * 16 + d];
  pe[idx] = s;
}

__global__ void concat_kernel(const float* __restrict__ x, const float* __restrict__ pe,
                              float* __restrict__ xc) {
  int idx = blockIdx.x * 256 + threadIdx.x;
  if (idx >= NN * CATK) return;
  int i = idx / CATK, c = idx - i * CATK;
  xc[idx] = (c < INCH) ? x[(size_t)i * INCH + c] : pe[(size_t)i * 16 + (c - INCH)];
}

// ---------------- generic fp32 GEMM: C[M][Nn] = A[M][K] @ W[K][Nn] + bias (+add1+add2) ----------------
// 64x64 tile, BK=16, 256 threads, 4x4 microtile.
__global__ __launch_bounds__(256) void gemm_f32_kernel(const float* __restrict__ A,
                                                       const float* __restrict__ W,
                                                       const float* __restrict__ bias,
                                                       const float* __restrict__ add1,
                                                       const float* __restrict__ add2,
                                                       float* __restrict__ C,
                                                       int M, int Nn, int K) {
  __shared__ float As[64][17];
  __shared__ float Ws[16][68];
  int tid = threadIdx.x;
  int m0 = blockIdx.y * 64, n0 = blockIdx.x * 64;
  int ty = tid >> 4, tx = tid & 15;
  float acc[4][4] = {};
  for (int k0 = 0; k0 < K; k0 += 16) {
    {
      int r = tid >> 2, kc = (tid & 3) * 4;
      float4 v = *(const float4*)(A + (size_t)(m0 + r) * K + k0 + kc);
      As[r][kc] = v.x; As[r][kc + 1] = v.y; As[r][kc + 2] = v.z; As[r][kc + 3] = v.w;
    }
    {
      int r = tid >> 4, nc = (tid & 15) * 4;
      float4 v = *(const float4*)(W + (size_t)(k0 + r) * Nn + n0 + nc);
      Ws[r][nc] = v.x; Ws[r][nc + 1] = v.y; Ws[r][nc + 2] = v.z; Ws[r][nc + 3] = v.w;
    }
    __syncthreads();
#pragma unroll
    for (int kk = 0; kk < 16; kk++) {
      float a4[4], b4[4];
#pragma unroll
      for (int i = 0; i < 4; i++) a4[i] = As[ty * 4 + i][kk];
#pragma unroll
      for (int j = 0; j < 4; j++) b4[j] = Ws[kk][tx * 4 + j];
#pragma unroll
      for (int i = 0; i < 4; i++)
#pragma unroll
        for (int j = 0; j < 4; j++) acc[i][j] += a4[i] * b4[j];
    }
    __syncthreads();
  }
#pragma unroll
  for (int i = 0; i < 4; i++) {
    int row = m0 + ty * 4 + i;
#pragma unroll
    for (int j = 0; j < 4; j++) {
      int col = n0 + tx * 4 + j;
      float r = acc[i][j];
      if (bias) r += bias[col];
      if (add1) r += add1[(size_t)row * Nn + col];
      if (add2) r += add2[(size_t)row * Nn + col];
      C[(size_t)row * Nn + col] = r;
    }
  }
}

// ---------------- attention ----------------
__global__ void score_kernel(const float* __restrict__ q, const float* __restrict__ k,
                             const int* __restrict__ sidx, const int* __restrict__ tidx,
                             float* __restrict__ scores) {
  int idx = blockIdx.x * 256 + threadIdx.x;
  if (idx >= NE * 4) return;
  int e = idx >> 2, h = idx & 3;
  int t = tidx[e], s = sidx[e];
  const float4* qp = (const float4*)(q + (size_t)t * HID + h * 64);
  const float4* kp = (const float4*)(k + (size_t)s * HID + h * 64);
  float acc = 0.f;
#pragma unroll
  for (int i = 0; i < 16; i++) {
    float4 a = qp[i], b = kp[i];
    acc += a.x * b.x + a.y * b.y + a.z * b.z + a.w * b.w;
  }
  scores[idx] = acc * 0.125f;  // 1/sqrt(64)
}

__global__ void csr_count_kernel(const int* __restrict__ tidx, int* __restrict__ cnt) {
  int e = blockIdx.x * 256 + threadIdx.x;
  if (e < NE) atomicAdd(&cnt[tidx[e]], 1);
}

__global__ void csr_scan_kernel(const int* __restrict__ cnt, int* __restrict__ off) {
  int lane = threadIdx.x;  // single wave of 64
  const int per = NN / 64; // 48
  int s = 0;
  for (int i = 0; i < per; i++) s += cnt[lane * per + i];
  int run = s;
  for (int d = 1; d < 64; d <<= 1) {
    int t = __shfl_up(run, d);
    if (lane >= d) run += t;
  }
  int acc = run - s;  // exclusive
  for (int i = 0; i < per; i++) {
    off[lane * per + i] = acc;
    acc += cnt[lane * per + i];
  }
  if (lane == 63) off[NN] = acc;
}

__global__ void csr_fill_kernel(const int* __restrict__ sidx, const int* __restrict__ tidx,
                                const int* __restrict__ off, int* __restrict__ cur,
                                int* __restrict__ eid, int* __restrict__ csrc) {
  int e = blockIdx.x * 256 + threadIdx.x;
  if (e >= NE) return;
  int t = tidx[e];
  int pos = atomicAdd(&cur[t], 1);
  int slot = off[t] + pos;
  eid[slot] = e;
  csrc[slot] = sidx[e];
}

// block per node, wave per head, lane per dim
__global__ void agg_kernel(const int* __restrict__ off, const int* __restrict__ eid,
                           const int* __restrict__ csrc, const float* __restrict__ scores,
                           const float* __restrict__ v, float* __restrict__ agg) {
  int node = blockIdx.x, tid = threadIdx.x;
  int h = tid >> 6, lane = tid & 63;
  int beg = off[node], end = off[node + 1];
  float m = -INFINITY;
  for (int i = beg + lane; i < end; i += 64) m = fmaxf(m, scores[eid[i] * 4 + h]);
  for (int d = 32; d; d >>= 1) m = fmaxf(m, __shfl_xor(m, d));
  float denom = 0.f, accv = 0.f;
  for (int i = beg; i < end; ++i) {
    float sc = scores[eid[i] * 4 + h];
    float ev = expf(sc - m);
    denom += ev;
    accv += ev * v[(size_t)csrc[i] * HID + h * 64 + lane];
  }
  agg[(size_t)node * HID + h * 64 + lane] = accv / fmaxf(denom, 1e-16f);
}

__global__ void ln_relu_kernel(const float* __restrict__ z, const float* __restrict__ g,
                               const float* __restrict__ b, float* __restrict__ out) {
  int row = blockIdx.x, tid = threadIdx.x;
  float v = z[(size_t)row * HID + tid];
  float s = v;
  for (int d = 32; d; d >>= 1) s += __shfl_xor(s, d);
  __shared__ float w4[4], w4b[4];
  int wv = tid >> 6, lane = tid & 63;
  if (lane == 0) w4[wv] = s;
  __syncthreads();
  float mu = (w4[0] + w4[1] + w4[2] + w4[3]) * (1.f / HID);
  float dv = v - mu;
  float q = dv * dv;
  for (int d = 32; d; d >>= 1) q += __shfl_xor(q, d);
  if (lane == 0) w4b[wv] = q;
  __syncthreads();
  float var = (w4b[0] + w4b[1] + w4b[2] + w4b[3]) * (1.f / HID);
  float y = dv * (1.f / sqrtf(var + 1e-5f)) * g[tid] + b[tid];
  out[(size_t)row * HID + tid] = fmaxf(y, 0.f);
}

__global__ void decode_kernel(const float* __restrict__ h, const int* __restrict__ src,
                              const int* __restrict__ dst, float* __restrict__ out) {
  int wv = threadIdx.x >> 6, lane = threadIdx.x & 63;
  int p = blockIdx.x * 4 + wv;
  if (p >= NP) return;
  const float4* a = (const float4*)(h + (size_t)src[p] * HID);
  const float4* b = (const float4*)(h + (size_t)dst[p] * HID);
  float4 x = a[lane], y = b[lane];
  float s = x.x * y.x + x.y * y.y + x.z * y.z + x.w * y.w;
  for (int d = 32; d; d >>= 1) s += __shfl_xor(s, d);
  if (lane == 0) out[p] = 1.f / (1.f + expf(-s));
}

// ---------------- host launch ----------------
extern "C" void kernel_launch(void* const* d_in, const int* in_sizes, int n_in,
                              void* d_out, int out_size, void* d_ws, size_t ws_size,
                              hipStream_t stream) {
  const float* x      = (const float*)d_in[0];
  const int*   ei     = (const int*)d_in[1];
  const int*   src    = (const int*)d_in[2];
  const int*   dst    = (const int*)d_in[3];
  const float* rwse_w = (const float*)d_in[4];
  const float* rwse_b = (const float*)d_in[5];
  const float* proj_w = (const float*)d_in[6];
  const float* proj_b = (const float*)d_in[7];
  const float* Wq     = (const float*)d_in[8];
  const float* bq     = (const float*)d_in[9];
  const float* Wk     = (const float*)d_in[10];
  const float* bk     = (const float*)d_in[11];
  const float* Wv     = (const float*)d_in[12];
  const float* bv     = (const float*)d_in[13];
  const float* Ws     = (const float*)d_in[14];
  const float* bs     = (const float*)d_in[15];
  const float* ln_g   = (const float*)d_in[16];
  const float* ln_b   = (const float*)d_in[17];
  float* out = (float*)d_out;

  const size_t MAT = (size_t)NN * NN * sizeof(_Float16);  // 18,874,368
  char* base = (char*)d_ws;
  _Float16* rw   = (_Float16*)(base + 0 * MAT);
  _Float16* rwT  = (_Float16*)(base + 1 * MAT);
  _Float16* rw2  = (_Float16*)(base + 2 * MAT);
  _Float16* rw2T = (_Float16*)(base + 3 * MAT);
  _Float16* rw3  = (_Float16*)(base + 4 * MAT);
  _Float16* rw3T = (_Float16*)(base + 5 * MAT);
  _Float16* rw4  = (_Float16*)(base + 6 * MAT);
  _Float16* rw4T = (_Float16*)(base + 7 * MAT);
  _Float16* rw8  = (_Float16*)(base + 8 * MAT);
  _Float16* rw12 = (_Float16*)(base + 9 * MAT);
  float* adj = (float*)(base + 8 * MAT);  // overlaps rw8/rw12: adj dead before they're written
  char* sm = base + 10 * MAT;
  float* diags  = (float*)sm; sm += (size_t)16 * NN * 4;
  float* pe     = (float*)sm; sm += (size_t)NN * 16 * 4;
  float* xc     = (float*)sm; sm += (size_t)NN * CATK * 4;
  float* hbuf   = (float*)sm; sm += (size_t)NN * HID * 4;
  float* qb     = (float*)sm; sm += (size_t)NN * HID * 4;
  float* kb     = (float*)sm; sm += (size_t)NN * HID * 4;
  float* vb     = (float*)sm; sm += (size_t)NN * HID * 4;
  float* aggb   = (float*)sm; sm += (size_t)NN * HID * 4;
  float* zb     = (float*)sm; sm += (size_t)NN * HID * 4;
  float* scores = (float*)sm; sm += (size_t)NE * 4 * 4;
  int* cnt = (int*)sm; sm += 12288;
  int* cur = (int*)sm; sm += 12288;
  int* off = (int*)sm; sm += 16384;
  int* eid = (int*)sm; sm += (size_t)NE * 4;
  int* csrc = (int*)sm; sm += (size_t)NE * 4;
  (void)in_sizes; (void)n_in; (void)out_size; (void)ws_size;

  const dim3 B256(256);
  const dim3 gT(NN / 64, NN / 64);      // transpose
  const dim3 gG(NN / 128, NN / 128);    // f16 GEMM
  const dim3 gS(HID / 64, NN / 64);     // fp32 GEMM [NN x HID]

  // --- RWSE ---
  hipMemsetAsync(adj, 0, (size_t)NN * NN * 4, stream);
  scatter_adj_kernel<<<(NE + 255) / 256, B256, 0, stream>>>(ei, adj);
  rownorm_kernel<<<NN, B256, 0, stream>>>(adj, rw);
  transpose_f16_kernel<<<gT, B256, 0, stream>>>((const unsigned short*)rw, (unsigned short*)rwT);
  gemm_f16_nt<<<gG, B256, 0, stream>>>(rw, rwT, rw2, NN);
  transpose_f16_kernel<<<gT, B256, 0, stream>>>((const unsigned short*)rw2, (unsigned short*)rw2T);
  gemm_f16_nt<<<gG, B256, 0, stream>>>(rw2, rwT, rw3, NN);
  transpose_f16_kernel<<<gT, B256, 0, stream>>>((const unsigned short*)rw3, (unsigned short*)rw3T);
  gemm_f16_nt<<<gG, B256, 0, stream>>>(rw3, rwT, rw4, NN);
  transpose_f16_kernel<<<gT, B256, 0, stream>>>((const unsigned short*)rw4, (unsigned short*)rw4T);
  gemm_f16_nt<<<gG, B256, 0, stream>>>(rw4, rw4T, rw8, NN);
  gemm_f16_nt<<<gG, B256, 0, stream>>>(rw8, rw4T, rw12, NN);

  diag_extract_kernel<<<NN / 256, B256, 0, stream>>>(rw,   diags + 0 * NN);
  diag_extract_kernel<<<NN / 256, B256, 0, stream>>>(rw2,  diags + 1 * NN);
  diag_extract_kernel<<<NN / 256, B256, 0, stream>>>(rw3,  diags + 2 * NN);
  diag_extract_kernel<<<NN / 256, B256, 0, stream>>>(rw4,  diags + 3 * NN);
  diag_prod_kernel<<<NN, B256, 0, stream>>>(rw,   rw4T, diags + 4 * NN);   // t=5
  diag_prod_kernel<<<NN, B256, 0, stream>>>(rw2,  rw4T, diags + 5 * NN);   // t=6
  diag_prod_kernel<<<NN, B256, 0, stream>>>(rw3,  rw4T, diags + 6 * NN);   // t=7
  diag_extract_kernel<<<NN / 256, B256, 0, stream>>>(rw8,  diags + 7 * NN);
  diag_prod_kernel<<<NN, B256, 0, stream>>>(rw8,  rwT,  diags + 8 * NN);   // t=9
  diag_prod_kernel<<<NN, B256, 0, stream>>>(rw8,  rw2T, diags + 9 * NN);   // t=10
  diag_prod_kernel<<<NN, B256, 0, stream>>>(rw8,  rw3T, diags + 10 * NN);  // t=11
  diag_extract_kernel<<<NN / 256, B256, 0, stream>>>(rw12, diags + 11 * NN);
  diag_prod_kernel<<<NN, B256, 0, stream>>>(rw12, rwT,  diags + 12 * NN);  // t=13
  diag_prod_kernel<<<NN, B256, 0, stream>>>(rw12, rw2T, diags + 13 * NN);  // t=14
  diag_prod_kernel<<<NN, B256, 0, stream>>>(rw12, rw3T, diags + 14 * NN);  // t=15
  diag_prod_kernel<<<NN, B256, 0, stream>>>(rw12, rw4T, diags + 15 * NN);  // t=16

  pe_kernel<<<(NN * 16) / 256, B256, 0, stream>>>(diags, rwse_w, rwse_b, pe);
  concat_kernel<<<(NN * CATK) / 256, B256, 0, stream>>>(x, pe, xc);
  gemm_f32_kernel<<<gS, B256, 0, stream>>>(xc, proj_w, proj_b, nullptr, nullptr, hbuf,
                                           NN, HID, CATK);

  // --- CSR by target (shared across layers) ---
  hipMemsetAsync(cnt, 0, 12288, stream);
  hipMemsetAsync(cur, 0, 12288, stream);
  csr_count_kernel<<<(NE + 255) / 256, B256, 0, stream>>>(ei + NE, cnt);
  csr_scan_kernel<<<1, 64, 0, stream>>>(cnt, off);
  csr_fill_kernel<<<(NE + 255) / 256, B256, 0, stream>>>(ei, ei + NE, off, cur, eid, csrc);

  // --- transformer layers ---
  for (int l = 0; l < 2; ++l) {
    const float* wq = Wq + (size_t)l * HID * HID;
    const float* wk = Wk + (size_t)l * HID * HID;
    const float* wv = Wv + (size_t)l * HID * HID;
    const float* ws = Ws + (size_t)l * HID * HID;
    gemm_f32_kernel<<<gS, B256, 0, stream>>>(hbuf, wq, bq + l * HID, nullptr, nullptr, qb, NN, HID, HID);
    gemm_f32_kernel<<<gS, B256, 0, stream>>>(hbuf, wk, bk + l * HID, nullptr, nullptr, kb, NN, HID, HID);
    gemm_f32_kernel<<<gS, B256, 0, stream>>>(hbuf, wv, bv + l * HID, nullptr, nullptr, vb, NN, HID, HID);
    score_kernel<<<(NE * 4) / 256, B256, 0, stream>>>(qb, kb, ei, ei + NE, scores);
    agg_kernel<<<NN, B256, 0, stream>>>(off, eid, csrc, scores, vb, aggb);
    // z = h + agg + h@Ws + bs
    gemm_f32_kernel<<<gS, B256, 0, stream>>>(hbuf, ws, bs + l * HID, hbuf, aggb, zb, NN, HID, HID);
    ln_relu_kernel<<<NN, B256, 0, stream>>>(zb, ln_g + l * HID, ln_b + l * HID, hbuf);
  }

  // --- link decode ---
  decode_kernel<<<NP / 4, B256, 0, stream>>>(hbuf, src, dst, out);
}

// Round 2
// 1052.934 us; speedup vs baseline: 1.1006x; 1.1006x over previous
//
#include <hip/hip_runtime.h>
#include <hip/hip_bf16.h>

#define NN   3072
#define NE   147456
#define NP   100000
#define HID  256
#define INCH 128
#define CATK 144
#define KPAD 160

typedef __attribute__((ext_vector_type(4))) float    f32x4;
typedef __attribute__((ext_vector_type(8))) _Float16 f16x8;

// ---------------- async global->LDS (16B) ----------------
__device__ __forceinline__ void gload16(const void* g, void* l) {
  __builtin_amdgcn_global_load_lds((const __attribute__((address_space(1))) void*)g,
                                   (__attribute__((address_space(3))) void*)l, 16, 0, 0);
}

// ---------------- adjacency build ----------------
__global__ void scatter_adj_kernel(const int* __restrict__ ei, float* __restrict__ adj) {
  int e = blockIdx.x * 256 + threadIdx.x;
  if (e < NE) {
    int s = ei[e], t = ei[NE + e];
    atomicAdd(&adj[(size_t)s * NN + t], 1.0f);
  }
}

// row-normalize: rw[i][j] = adj[i][j] / max(rowsum, 1)   (fp16 out)
__global__ void rownorm_kernel(const float* __restrict__ adj, _Float16* __restrict__ rw) {
  int row = blockIdx.x, tid = threadIdx.x;
  const float* ap = adj + (size_t)row * NN;
  float s = 0.f;
  for (int j = tid; j < NN; j += 256) s += ap[j];
  for (int d = 32; d; d >>= 1) s += __shfl_xor(s, d);
  __shared__ float w4[4];
  if ((tid & 63) == 0) w4[tid >> 6] = s;
  __syncthreads();
  float inv = 1.f / fmaxf(w4[0] + w4[1] + w4[2] + w4[3], 1.f);
  _Float16* rp = rw + (size_t)row * NN;
  for (int j = tid; j < NN; j += 256) rp[j] = (_Float16)(ap[j] * inv);
}

// ---------------- fp16 64x64-tiled transpose ----------------
__global__ void transpose_f16_kernel(const unsigned short* __restrict__ in,
                                     unsigned short* __restrict__ out) {
  __shared__ unsigned short t[64][65];
  int bx = blockIdx.x, by = blockIdx.y, tid = threadIdx.x;
#pragma unroll
  for (int ii = 0; ii < 16; ii++) {
    int lin = ii * 256 + tid, r = lin >> 6, c = lin & 63;
    t[r][c] = in[(size_t)(by * 64 + r) * NN + bx * 64 + c];
  }
  __syncthreads();
#pragma unroll
  for (int ii = 0; ii < 16; ii++) {
    int lin = ii * 256 + tid, r = lin >> 6, c = lin & 63;
    out[(size_t)(bx * 64 + r) * NN + by * 64 + c] = t[c][r];
  }
}

// ---------------- fp16 MFMA GEMM: C = A * Bt^T  (both row-major [n][n]) ----------------
__global__ __launch_bounds__(256) void gemm_f16_nt(const _Float16* __restrict__ A,
                                                   const _Float16* __restrict__ Bt,
                                                   _Float16* __restrict__ C, int n) {
  __shared__ _Float16 As[128 * 32];
  __shared__ _Float16 Bs[128 * 32];
  const int tid = threadIdx.x;
  const int lane = tid & 63, wave = tid >> 6;
  const int wr = wave >> 1, wc = wave & 1;
  const int rowA0 = blockIdx.y * 128, rowB0 = blockIdx.x * 128;
  const int fr = lane & 15;
  const int fk = (lane >> 4) * 8;
  const int ldsoff = tid * 8;
  const int gr = tid >> 2, gc = (tid & 3) * 8;
  f32x4 acc[4][4] = {};
  const int nkt = n >> 5;
  for (int kt = 0; kt < nkt; ++kt) {
    const int k0 = kt << 5;
    const _Float16* ga = A + (size_t)(rowA0 + gr) * n + k0 + gc;
    const _Float16* gb = Bt + (size_t)(rowB0 + gr) * n + k0 + gc;
    gload16(ga, As + ldsoff);
    gload16(ga + (size_t)64 * n, As + 2048 + ldsoff);
    gload16(gb, Bs + ldsoff);
    gload16(gb + (size_t)64 * n, Bs + 2048 + ldsoff);
    __syncthreads();
    f16x8 af[4], bf[4];
#pragma unroll
    for (int i = 0; i < 4; i++) {
      af[i] = *(const f16x8*)(As + (wr * 64 + i * 16 + fr) * 32 + fk);
      bf[i] = *(const f16x8*)(Bs + (wc * 64 + i * 16 + fr) * 32 + fk);
    }
#pragma unroll
    for (int i = 0; i < 4; i++)
#pragma unroll
      for (int j = 0; j < 4; j++)
        acc[i][j] = __builtin_amdgcn_mfma_f32_16x16x32_f16(af[i], bf[j], acc[i][j], 0, 0, 0);
    __syncthreads();
  }
  const int crow0 = rowA0 + wr * 64, ccol0 = rowB0 + wc * 64;
#pragma unroll
  for (int i = 0; i < 4; i++)
#pragma unroll
    for (int j = 0; j < 4; j++)
#pragma unroll
      for (int r = 0; r < 4; r++) {
        int row = crow0 + i * 16 + (lane >> 4) * 4 + r;
        int col = ccol0 + j * 16 + (lane & 15);
        C[(size_t)row * n + col] = (_Float16)acc[i][j][r];
      }
}

// ---------------- fp16 MFMA node GEMM: C[M][Nn] = A[M][K] @ Bt[Nn][K]^T + epilogue ----
// 64x64 tile, 4 waves (each 32x32 = 2x2 frags), BK=32.
__global__ __launch_bounds__(256) void gemm_f16_node(const _Float16* __restrict__ A,
                                                     const _Float16* __restrict__ Bt,
                                                     const float* __restrict__ bias,
                                                     const float* __restrict__ add1,
                                                     const float* __restrict__ add2,
                                                     float* __restrict__ C,
                                                     _Float16* __restrict__ C16,
                                                     int M, int Nn, int K) {
  __shared__ _Float16 As[64 * 32];
  __shared__ _Float16 Bs[64 * 32];
  const int tid = threadIdx.x;
  const int lane = tid & 63, wave = tid >> 6;
  const int wr = wave >> 1, wc = wave & 1;
  const int m0 = blockIdx.y * 64, n0 = blockIdx.x * 64;
  const int fr = lane & 15, fk = (lane >> 4) * 8;
  const int gr = tid >> 2, gc = (tid & 3) * 8;
  f32x4 acc[2][2] = {};
  for (int k0 = 0; k0 < K; k0 += 32) {
    gload16(A + (size_t)(m0 + gr) * K + k0 + gc, As + tid * 8);
    gload16(Bt + (size_t)(n0 + gr) * K + k0 + gc, Bs + tid * 8);
    __syncthreads();
    f16x8 af[2], bf[2];
#pragma unroll
    for (int i = 0; i < 2; i++) {
      af[i] = *(const f16x8*)(As + (wr * 32 + i * 16 + fr) * 32 + fk);
      bf[i] = *(const f16x8*)(Bs + (wc * 32 + i * 16 + fr) * 32 + fk);
    }
#pragma unroll
    for (int i = 0; i < 2; i++)
#pragma unroll
      for (int j = 0; j < 2; j++)
        acc[i][j] = __builtin_amdgcn_mfma_f32_16x16x32_f16(af[i], bf[j], acc[i][j], 0, 0, 0);
    __syncthreads();
  }
  const int crow0 = m0 + wr * 32, ccol0 = n0 + wc * 32;
#pragma unroll
  for (int i = 0; i < 2; i++)
#pragma unroll
    for (int j = 0; j < 2; j++)
#pragma unroll
      for (int r = 0; r < 4; r++) {
        int row = crow0 + i * 16 + (lane >> 4) * 4 + r;
        int col = ccol0 + j * 16 + (lane & 15);
        float val = acc[i][j][r];
        if (bias) val += bias[col];
        if (add1) val += add1[(size_t)row * Nn + col];
        if (add2) val += add2[(size_t)row * Nn + col];
        C[(size_t)row * Nn + col] = val;
        if (C16) C16[(size_t)row * Nn + col] = (_Float16)val;
      }
}

// W [K][N] f32 -> Wt [N][Kpad] f16 (zero-padded K)
__global__ void wconv_kernel(const float* __restrict__ W, _Float16* __restrict__ Wt,
                             int K, int N, int Kpad) {
  int idx = blockIdx.x * 256 + threadIdx.x;
  if (idx >= N * Kpad) return;
  int n = idx / Kpad, k = idx - n * Kpad;
  Wt[idx] = (k < K) ? (_Float16)W[(size_t)k * N + n] : (_Float16)0.f;
}

// ---------------- diagonals ----------------
__global__ void diag_extract_kernel(const _Float16* __restrict__ M, float* __restrict__ out) {
  int i = blockIdx.x * 256 + threadIdx.x;
  if (i < NN) out[i] = (float)M[(size_t)i * (NN + 1)];
}

__device__ __forceinline__ float blk_reduce(float s, float* w4, int tid) {
  for (int d = 32; d; d >>= 1) s += __shfl_xor(s, d);
  if ((tid & 63) == 0) w4[tid >> 6] = s;
  __syncthreads();
  return w4[0] + w4[1] + w4[2] + w4[3];
}

// o_k[i] = sum_j Xk[i,j]*Yt[i,j], three left operands share one right
__global__ void diag_prod3x1_kernel(const _Float16* __restrict__ X1, const _Float16* __restrict__ X2,
                                    const _Float16* __restrict__ X3, const _Float16* __restrict__ Yt,
                                    float* __restrict__ o1, float* __restrict__ o2,
                                    float* __restrict__ o3) {
  int row = blockIdx.x, tid = threadIdx.x;
  const f16x8* yp = (const f16x8*)(Yt + (size_t)row * NN);
  const f16x8* x1 = (const f16x8*)(X1 + (size_t)row * NN);
  const f16x8* x2 = (const f16x8*)(X2 + (size_t)row * NN);
  const f16x8* x3 = (const f16x8*)(X3 + (size_t)row * NN);
  float s1 = 0.f, s2 = 0.f, s3 = 0.f;
  for (int j = tid; j < NN / 8; j += 256) {
    f16x8 y = yp[j], a = x1[j], b = x2[j], c = x3[j];
#pragma unroll
    for (int r = 0; r < 8; r++) {
      float yv = (float)y[r];
      s1 += (float)a[r] * yv; s2 += (float)b[r] * yv; s3 += (float)c[r] * yv;
    }
  }
  __shared__ float w4[4];
  float t1 = blk_reduce(s1, w4, tid); __syncthreads();
  float t2 = blk_reduce(s2, w4, tid); __syncthreads();
  float t3 = blk_reduce(s3, w4, tid);
  if (tid == 0) { o1[row] = t1; o2[row] = t2; o3[row] = t3; }
}

// o_k[i] = sum_j X[i,j]*Ykt[i,j], one left shared across 3 rights
__global__ void diag_prod1x3_kernel(const _Float16* __restrict__ X, const _Float16* __restrict__ Y1,
                                    const _Float16* __restrict__ Y2, const _Float16* __restrict__ Y3,
                                    float* __restrict__ o1, float* __restrict__ o2,
                                    float* __restrict__ o3) {
  int row = blockIdx.x, tid = threadIdx.x;
  const f16x8* xp = (const f16x8*)(X + (size_t)row * NN);
  const f16x8* y1 = (const f16x8*)(Y1 + (size_t)row * NN);
  const f16x8* y2 = (const f16x8*)(Y2 + (size_t)row * NN);
  const f16x8* y3 = (const f16x8*)(Y3 + (size_t)row * NN);
  float s1 = 0.f, s2 = 0.f, s3 = 0.f;
  for (int j = tid; j < NN / 8; j += 256) {
    f16x8 x = xp[j], a = y1[j], b = y2[j], c = y3[j];
#pragma unroll
    for (int r = 0; r < 8; r++) {
      float xv = (float)x[r];
      s1 += xv * (float)a[r]; s2 += xv * (float)b[r]; s3 += xv * (float)c[r];
    }
  }
  __shared__ float w4[4];
  float t1 = blk_reduce(s1, w4, tid); __syncthreads();
  float t2 = blk_reduce(s2, w4, tid); __syncthreads();
  float t3 = blk_reduce(s3, w4, tid);
  if (tid == 0) { o1[row] = t1; o2[row] = t2; o3[row] = t3; }
}

__global__ void diag_prod1x4_kernel(const _Float16* __restrict__ X, const _Float16* __restrict__ Y1,
                                    const _Float16* __restrict__ Y2, const _Float16* __restrict__ Y3,
                                    const _Float16* __restrict__ Y4,
                                    float* __restrict__ o1, float* __restrict__ o2,
                                    float* __restrict__ o3, float* __restrict__ o4) {
  int row = blockIdx.x, tid = threadIdx.x;
  const f16x8* xp = (const f16x8*)(X + (size_t)row * NN);
  const f16x8* y1 = (const f16x8*)(Y1 + (size_t)row * NN);
  const f16x8* y2 = (const f16x8*)(Y2 + (size_t)row * NN);
  const f16x8* y3 = (const f16x8*)(Y3 + (size_t)row * NN);
  const f16x8* y4 = (const f16x8*)(Y4 + (size_t)row * NN);
  float s1 = 0.f, s2 = 0.f, s3 = 0.f, s4 = 0.f;
  for (int j = tid; j < NN / 8; j += 256) {
    f16x8 x = xp[j], a = y1[j], b = y2[j], c = y3[j], d = y4[j];
#pragma unroll
    for (int r = 0; r < 8; r++) {
      float xv = (float)x[r];
      s1 += xv * (float)a[r]; s2 += xv * (float)b[r];
      s3 += xv * (float)c[r]; s4 += xv * (float)d[r];
    }
  }
  __shared__ float w4[4];
  float t1 = blk_reduce(s1, w4, tid); __syncthreads();
  float t2 = blk_reduce(s2, w4, tid); __syncthreads();
  float t3 = blk_reduce(s3, w4, tid); __syncthreads();
  float t4 = blk_reduce(s4, w4, tid);
  if (tid == 0) { o1[row] = t1; o2[row] = t2; o3[row] = t3; o4[row] = t4; }
}

// pe[i][d] = b[d] + sum_t diags[t][i] * w[t][d]
__global__ void pe_kernel(const float* __restrict__ diags, const float* __restrict__ w,
                          const float* __restrict__ b, float* __restrict__ pe) {
  int idx = blockIdx.x * 256 + threadIdx.x;
  if (idx >= NN * 16) return;
  int i = idx >> 4, d = idx & 15;
  float s = b[d];
#pragma unroll
  for (int t = 0; t < 16; t++) s += diags[t * NN + i] * w[t * 16 + d];
  pe[idx] = s;
}

// concat to fp16 with zero pad to KPAD
__global__ void concat16_kernel(const float* __restrict__ x, const float* __restrict__ pe,
                                _Float16* __restrict__ xc) {
  int idx = blockIdx.x * 256 + threadIdx.x;
  if (idx >= NN * KPAD) return;
  int i = idx / KPAD, c = idx - i * KPAD;
  float v = (c < INCH) ? x[(size_t)i * INCH + c]
                       : (c < CATK ? pe[(size_t)i * 16 + (c - INCH)] : 0.f);
  xc[idx] = (_Float16)v;
}

// ---------------- attention ----------------
__global__ void score_kernel(const float* __restrict__ q, const float* __restrict__ k,
                             const int* __restrict__ sidx, const int* __restrict__ tidx,
                             float* __restrict__ scores) {
  int idx = blockIdx.x * 256 + threadIdx.x;
  if (idx >= NE * 4) return;
  int e = idx >> 2, h = idx & 3;
  int t = tidx[e], s = sidx[e];
  const float4* qp = (const float4*)(q + (size_t)t * HID + h * 64);
  const float4* kp = (const float4*)(k + (size_t)s * HID + h * 64);
  float acc = 0.f;
#pragma unroll
  for (int i = 0; i < 16; i++) {
    float4 a = qp[i], b = kp[i];
    acc += a.x * b.x + a.y * b.y + a.z * b.z + a.w * b.w;
  }
  scores[idx] = acc * 0.125f;  // 1/sqrt(64)
}

__global__ void csr_count_kernel(const int* __restrict__ tidx, int* __restrict__ cnt) {
  int e = blockIdx.x * 256 + threadIdx.x;
  if (e < NE) atomicAdd(&cnt[tidx[e]], 1);
}

__global__ void csr_scan_kernel(const int* __restrict__ cnt, int* __restrict__ off) {
  int lane = threadIdx.x;  // single wave of 64
  const int per = NN / 64; // 48
  int s = 0;
  for (int i = 0; i < per; i++) s += cnt[lane * per + i];
  int run = s;
  for (int d = 1; d < 64; d <<= 1) {
    int t = __shfl_up(run, d);
    if (lane >= d) run += t;
  }
  int acc = run - s;  // exclusive
  for (int i = 0; i < per; i++) {
    off[lane * per + i] = acc;
    acc += cnt[lane * per + i];
  }
  if (lane == 63) off[NN] = acc;
}

__global__ void csr_fill_kernel(const int* __restrict__ sidx, const int* __restrict__ tidx,
                                const int* __restrict__ off, int* __restrict__ cur,
                                int* __restrict__ eid, int* __restrict__ csrc) {
  int e = blockIdx.x * 256 + threadIdx.x;
  if (e >= NE) return;
  int t = tidx[e];
  int pos = atomicAdd(&cur[t], 1);
  int slot = off[t] + pos;
  eid[slot] = e;
  csrc[slot] = sidx[e];
}

// block per node, wave per head, lane per dim
__global__ void agg_kernel(const int* __restrict__ off, const int* __restrict__ eid,
                           const int* __restrict__ csrc, const float* __restrict__ scores,
                           const float* __restrict__ v, float* __restrict__ agg) {
  int node = blockIdx.x, tid = threadIdx.x;
  int h = tid >> 6, lane = tid & 63;
  int beg = off[node], end = off[node + 1];
  float m = -INFINITY;
  for (int i = beg + lane; i < end; i += 64) m = fmaxf(m, scores[eid[i] * 4 + h]);
  for (int d = 32; d; d >>= 1) m = fmaxf(m, __shfl_xor(m, d));
  float denom = 0.f, accv = 0.f;
  for (int i = beg; i < end; ++i) {
    float sc = scores[eid[i] * 4 + h];
    float ev = expf(sc - m);
    denom += ev;
    accv += ev * v[(size_t)csrc[i] * HID + h * 64 + lane];
  }
  agg[(size_t)node * HID + h * 64 + lane] = accv / fmaxf(denom, 1e-16f);
}

__global__ void ln_relu_kernel(const float* __restrict__ z, const float* __restrict__ g,
                               const float* __restrict__ b, float* __restrict__ out,
                               _Float16* __restrict__ out16) {
  int row = blockIdx.x, tid = threadIdx.x;
  float v = z[(size_t)row * HID + tid];
  float s = v;
  for (int d = 32; d; d >>= 1) s += __shfl_xor(s, d);
  __shared__ float w4[4], w4b[4];
  int wv = tid >> 6, lane = tid & 63;
  if (lane == 0) w4[wv] = s;
  __syncthreads();
  float mu = (w4[0] + w4[1] + w4[2] + w4[3]) * (1.f / HID);
  float dv = v - mu;
  float q = dv * dv;
  for (int d = 32; d; d >>= 1) q += __shfl_xor(q, d);
  if (lane == 0) w4b[wv] = q;
  __syncthreads();
  float var = (w4b[0] + w4b[1] + w4b[2] + w4b[3]) * (1.f / HID);
  float y = dv * (1.f / sqrtf(var + 1e-5f)) * g[tid] + b[tid];
  y = fmaxf(y, 0.f);
  out[(size_t)row * HID + tid] = y;
  out16[(size_t)row * HID + tid] = (_Float16)y;
}

__global__ void decode_kernel(const float* __restrict__ h, const int* __restrict__ src,
                              const int* __restrict__ dst, float* __restrict__ out) {
  int wv = threadIdx.x >> 6, lane = threadIdx.x & 63;
  int p = blockIdx.x * 4 + wv;
  if (p >= NP) return;
  const float4* a = (const float4*)(h + (size_t)src[p] * HID);
  const float4* b = (const float4*)(h + (size_t)dst[p] * HID);
  float4 x = a[lane], y = b[lane];
  float s = x.x * y.x + x.y * y.y + x.z * y.z + x.w * y.w;
  for (int d = 32; d; d >>= 1) s += __shfl_xor(s, d);
  if (lane == 0) out[p] = 1.f / (1.f + expf(-s));
}

// ---------------- host launch ----------------
extern "C" void kernel_launch(void* const* d_in, const int* in_sizes, int n_in,
                              void* d_out, int out_size, void* d_ws, size_t ws_size,
                              hipStream_t stream) {
  const float* x      = (const float*)d_in[0];
  const int*   ei     = (const int*)d_in[1];
  const int*   src    = (const int*)d_in[2];
  const int*   dst    = (const int*)d_in[3];
  const float* rwse_w = (const float*)d_in[4];
  const float* rwse_b = (const float*)d_in[5];
  const float* proj_w = (const float*)d_in[6];
  const float* proj_b = (const float*)d_in[7];
  const float* Wq     = (const float*)d_in[8];
  const float* bq     = (const float*)d_in[9];
  const float* Wk     = (const float*)d_in[10];
  const float* bk     = (const float*)d_in[11];
  const float* Wv     = (const float*)d_in[12];
  const float* bv     = (const float*)d_in[13];
  const float* Ws     = (const float*)d_in[14];
  const float* bs     = (const float*)d_in[15];
  const float* ln_g   = (const float*)d_in[16];
  const float* ln_b   = (const float*)d_in[17];
  float* out = (float*)d_out;

  const size_t MAT = (size_t)NN * NN * sizeof(_Float16);  // 18,874,368
  char* base = (char*)d_ws;
  _Float16* rw   = (_Float16*)(base + 0 * MAT);
  _Float16* rwT  = (_Float16*)(base + 1 * MAT);
  _Float16* rw2  = (_Float16*)(base + 2 * MAT);
  _Float16* rw2T = (_Float16*)(base + 3 * MAT);
  _Float16* rw3  = (_Float16*)(base + 4 * MAT);
  _Float16* rw3T = (_Float16*)(base + 5 * MAT);
  _Float16* rw4  = (_Float16*)(base + 6 * MAT);
  _Float16* rw4T = (_Float16*)(base + 7 * MAT);
  _Float16* rw8  = (_Float16*)(base + 8 * MAT);
  _Float16* rw12 = (_Float16*)(base + 9 * MAT);
  float* adj = (float*)(base + 8 * MAT);  // overlaps rw8/rw12: adj dead before they're written
  char* sm = base + 10 * MAT;
  float* diags  = (float*)sm; sm += (size_t)16 * NN * 4;
  float* pe     = (float*)sm; sm += (size_t)NN * 16 * 4;
  float* hbuf   = (float*)sm; sm += (size_t)NN * HID * 4;
  float* qb     = (float*)sm; sm += (size_t)NN * HID * 4;
  float* kb     = (float*)sm; sm += (size_t)NN * HID * 4;
  float* vb     = (float*)sm; sm += (size_t)NN * HID * 4;
  float* aggb   = (float*)sm; sm += (size_t)NN * HID * 4;
  float* zb     = (float*)sm; sm += (size_t)NN * HID * 4;
  float* scores = (float*)sm; sm += (size_t)NE * 4 * 4;
  int* cnt = (int*)sm; sm += 12288;
  int* cur = (int*)sm; sm += 12288;
  int* off = (int*)sm; sm += 16384;
  int* eid = (int*)sm; sm += (size_t)NE * 4;
  int* csrc = (int*)sm; sm += (size_t)NE * 4;
  _Float16* h16  = (_Float16*)sm; sm += (size_t)NN * HID * 2;
  _Float16* xc16 = (_Float16*)sm; sm += (size_t)NN * KPAD * 2;
  _Float16* wt_proj = (_Float16*)sm; sm += (size_t)HID * KPAD * 2;
  _Float16* wt_q[2]; _Float16* wt_k[2]; _Float16* wt_v[2]; _Float16* wt_s[2];
  for (int l = 0; l < 2; ++l) {
    wt_q[l] = (_Float16*)sm; sm += (size_t)HID * HID * 2;
    wt_k[l] = (_Float16*)sm; sm += (size_t)HID * HID * 2;
    wt_v[l] = (_Float16*)sm; sm += (size_t)HID * HID * 2;
    wt_s[l] = (_Float16*)sm; sm += (size_t)HID * HID * 2;
  }
  (void)in_sizes; (void)n_in; (void)out_size; (void)ws_size;

  const dim3 B256(256);
  const dim3 gT(NN / 64, NN / 64);      // transpose
  const dim3 gG(NN / 128, NN / 128);    // f16 big GEMM
  const dim3 gN(HID / 64, NN / 64);     // node GEMM [NN x HID]
  const int WG = (HID * HID + 255) / 256;

  // --- weight prep (independent of everything else) ---
  wconv_kernel<<<(HID * KPAD + 255) / 256, B256, 0, stream>>>(proj_w, wt_proj, CATK, HID, KPAD);
  for (int l = 0; l < 2; ++l) {
    wconv_kernel<<<WG, B256, 0, stream>>>(Wq + (size_t)l * HID * HID, wt_q[l], HID, HID, HID);
    wconv_kernel<<<WG, B256, 0, stream>>>(Wk + (size_t)l * HID * HID, wt_k[l], HID, HID, HID);
    wconv_kernel<<<WG, B256, 0, stream>>>(Wv + (size_t)l * HID * HID, wt_v[l], HID, HID, HID);
    wconv_kernel<<<WG, B256, 0, stream>>>(Ws + (size_t)l * HID * HID, wt_s[l], HID, HID, HID);
  }

  // --- RWSE ---
  hipMemsetAsync(adj, 0, (size_t)NN * NN * 4, stream);
  scatter_adj_kernel<<<(NE + 255) / 256, B256, 0, stream>>>(ei, adj);
  rownorm_kernel<<<NN, B256, 0, stream>>>(adj, rw);
  transpose_f16_kernel<<<gT, B256, 0, stream>>>((const unsigned short*)rw, (unsigned short*)rwT);
  gemm_f16_nt<<<gG, B256, 0, stream>>>(rw, rwT, rw2, NN);
  transpose_f16_kernel<<<gT, B256, 0, stream>>>((const unsigned short*)rw2, (unsigned short*)rw2T);
  gemm_f16_nt<<<gG, B256, 0, stream>>>(rw2, rwT, rw3, NN);
  transpose_f16_kernel<<<gT, B256, 0, stream>>>((const unsigned short*)rw3, (unsigned short*)rw3T);
  gemm_f16_nt<<<gG, B256, 0, stream>>>(rw3, rwT, rw4, NN);
  transpose_f16_kernel<<<gT, B256, 0, stream>>>((const unsigned short*)rw4, (unsigned short*)rw4T);
  gemm_f16_nt<<<gG, B256, 0, stream>>>(rw4, rw4T, rw8, NN);
  gemm_f16_nt<<<gG, B256, 0, stream>>>(rw8, rw4T, rw12, NN);

  diag_extract_kernel<<<NN / 256, B256, 0, stream>>>(rw,   diags + 0 * NN);
  diag_extract_kernel<<<NN / 256, B256, 0, stream>>>(rw2,  diags + 1 * NN);
  diag_extract_kernel<<<NN / 256, B256, 0, stream>>>(rw3,  diags + 2 * NN);
  diag_extract_kernel<<<NN / 256, B256, 0, stream>>>(rw4,  diags + 3 * NN);
  diag_prod3x1_kernel<<<NN, B256, 0, stream>>>(rw, rw2, rw3, rw4T,
                                               diags + 4 * NN, diags + 5 * NN, diags + 6 * NN);
  diag_extract_kernel<<<NN / 256, B256, 0, stream>>>(rw8,  diags + 7 * NN);
  diag_prod1x3_kernel<<<NN, B256, 0, stream>>>(rw8, rwT, rw2T, rw3T,
                                               diags + 8 * NN, diags + 9 * NN, diags + 10 * NN);
  diag_extract_kernel<<<NN / 256, B256, 0, stream>>>(rw12, diags + 11 * NN);
  diag_prod1x4_kernel<<<NN, B256, 0, stream>>>(rw12, rwT, rw2T, rw3T, rw4T,
                                               diags + 12 * NN, diags + 13 * NN,
                                               diags + 14 * NN, diags + 15 * NN);

  pe_kernel<<<(NN * 16) / 256, B256, 0, stream>>>(diags, rwse_w, rwse_b, pe);
  concat16_kernel<<<(NN * KPAD + 255) / 256, B256, 0, stream>>>(x, pe, xc16);
  // h = concat @ proj_w + proj_b   (writes fp32 hbuf + fp16 h16)
  gemm_f16_node<<<gN, B256, 0, stream>>>(xc16, wt_proj, proj_b, nullptr, nullptr,
                                         hbuf, h16, NN, HID, KPAD);

  // --- CSR by target (shared across layers) ---
  hipMemsetAsync(cnt, 0, 12288, stream);
  hipMemsetAsync(cur, 0, 12288, stream);
  csr_count_kernel<<<(NE + 255) / 256, B256, 0, stream>>>(ei + NE, cnt);
  csr_scan_kernel<<<1, 64, 0, stream>>>(cnt, off);
  csr_fill_kernel<<<(NE + 255) / 256, B256, 0, stream>>>(ei, ei + NE, off, cur, eid, csrc);

  // --- transformer layers ---
  for (int l = 0; l < 2; ++l) {
    gemm_f16_node<<<gN, B256, 0, stream>>>(h16, wt_q[l], bq + l * HID, nullptr, nullptr,
                                           qb, nullptr, NN, HID, HID);
    gemm_f16_node<<<gN, B256, 0, stream>>>(h16, wt_k[l], bk + l * HID, nullptr, nullptr,
                                           kb, nullptr, NN, HID, HID);
    gemm_f16_node<<<gN, B256, 0, stream>>>(h16, wt_v[l], bv + l * HID, nullptr, nullptr,
                                           vb, nullptr, NN, HID, HID);
    score_kernel<<<(NE * 4) / 256, B256, 0, stream>>>(qb, kb, ei, ei + NE, scores);
    agg_kernel<<<NN, B256, 0, stream>>>(off, eid, csrc, scores, vb, aggb);
    // z = h + agg + h@Ws + bs
    gemm_f16_node<<<gN, B256, 0, stream>>>(h16, wt_s[l], bs + l * HID, hbuf, aggb,
                                           zb, nullptr, NN, HID, HID);
    ln_relu_kernel<<<NN, B256, 0, stream>>>(zb, ln_g + l * HID, ln_b + l * HID, hbuf, h16);
  }

  // --- link decode ---
  decode_kernel<<<NP / 4, B256, 0, stream>>>(hbuf, src, dst, out);
}

// Round 3
// 853.914 us; speedup vs baseline: 1.3571x; 1.2331x over previous
//
#include <hip/hip_runtime.h>
#include <hip/hip_bf16.h>

#define NN   3072
#define NE   147456
#define NP   100000
#define HID  256
#define INCH 128
#define CATK 144
#define KPAD 160

typedef __attribute__((ext_vector_type(4))) float    f32x4;
typedef __attribute__((ext_vector_type(8))) _Float16 f16x8;

// ---------------- async global->LDS (16B) ----------------
__device__ __forceinline__ void gload16(const void* g, void* l) {
  __builtin_amdgcn_global_load_lds((const __attribute__((address_space(1))) void*)g,
                                   (__attribute__((address_space(3))) void*)l, 16, 0, 0);
}

// ---------------- adjacency build + in-degree count (one edge pass) ----------------
__global__ void edges_kernel(const int* __restrict__ ei, float* __restrict__ adj,
                             int* __restrict__ cnt) {
  int e = blockIdx.x * 256 + threadIdx.x;
  if (e < NE) {
    int s = ei[e], t = ei[NE + e];
    atomicAdd(&adj[(size_t)s * NN + t], 1.0f);
    atomicAdd(&cnt[t], 1);
  }
}

// row-normalize: rw[i][j] = adj[i][j] / max(rowsum, 1)   (fp16 out)
__global__ void rownorm_kernel(const float* __restrict__ adj, _Float16* __restrict__ rw) {
  int row = blockIdx.x, tid = threadIdx.x;
  const float* ap = adj + (size_t)row * NN;
  float s = 0.f;
  for (int j = tid; j < NN; j += 256) s += ap[j];
  for (int d = 32; d; d >>= 1) s += __shfl_xor(s, d);
  __shared__ float w4[4];
  if ((tid & 63) == 0) w4[tid >> 6] = s;
  __syncthreads();
  float inv = 1.f / fmaxf(w4[0] + w4[1] + w4[2] + w4[3], 1.f);
  _Float16* rp = rw + (size_t)row * NN;
  for (int j = tid; j < NN; j += 256) rp[j] = (_Float16)(ap[j] * inv);
}

// ---------------- fp16 64x64-tiled transpose ----------------
__global__ void transpose_f16_kernel(const unsigned short* __restrict__ in,
                                     unsigned short* __restrict__ out) {
  __shared__ unsigned short t[64][65];
  int bx = blockIdx.x, by = blockIdx.y, tid = threadIdx.x;
#pragma unroll
  for (int ii = 0; ii < 16; ii++) {
    int lin = ii * 256 + tid, r = lin >> 6, c = lin & 63;
    t[r][c] = in[(size_t)(by * 64 + r) * NN + bx * 64 + c];
  }
  __syncthreads();
#pragma unroll
  for (int ii = 0; ii < 16; ii++) {
    int lin = ii * 256 + tid, r = lin >> 6, c = lin & 63;
    out[(size_t)(bx * 64 + r) * NN + by * 64 + c] = t[c][r];
  }
}

// ---------------- fp16 MFMA GEMM: C = A * Bt^T  (row-major [n][n]) ----------------
// 128x128 tile, BK=64, 4 waves, both-sides XOR-swizzled LDS (chunk ^= row&7),
// XCD-chunked block swizzle (1D grid, nb % 8 == 0).
__global__ __launch_bounds__(256) void gemm_f16_nt(const _Float16* __restrict__ A,
                                                   const _Float16* __restrict__ Bt,
                                                   _Float16* __restrict__ C, int n) {
  __shared__ _Float16 As[128 * 64];
  __shared__ _Float16 Bs[128 * 64];
  const int nbx = n >> 7;
  const int nb = nbx * nbx;
  const int bid = blockIdx.x;
  const int cpx = nb >> 3;
  const int wg = (bid & 7) * cpx + (bid >> 3);
  const int by = wg / nbx, bx = wg % nbx;
  const int tid = threadIdx.x;
  const int lane = tid & 63, wave = tid >> 6;
  const int wr = wave >> 1, wc = wave & 1;
  const int rowA0 = by * 128, rowB0 = bx * 128;
  const int fr = lane & 15;
  const int rd = tid >> 3;   // stage row base 0..31
  const int cd = tid & 7;    // stage chunk 0..7
  f32x4 acc[4][4] = {};
  const int nkt = n >> 6;
  for (int kt = 0; kt < nkt; ++kt) {
    const int k0 = kt << 6;
#pragma unroll
    for (int s = 0; s < 4; s++) {
      const int row = rd + s * 32;
      const int cg = (cd ^ (row & 7)) << 3;   // inverse-swizzled global chunk
      gload16(A + (size_t)(rowA0 + row) * n + k0 + cg, As + row * 64 + cd * 8);
      gload16(Bt + (size_t)(rowB0 + row) * n + k0 + cg, Bs + row * 64 + cd * 8);
    }
    __syncthreads();
#pragma unroll
    for (int ks = 0; ks < 2; ks++) {
      const int ch = ks * 4 + (lane >> 4);
      f16x8 af[4], bf[4];
#pragma unroll
      for (int i = 0; i < 4; i++) {
        const int Ra = wr * 64 + i * 16 + fr;
        const int Rb = wc * 64 + i * 16 + fr;
        af[i] = *(const f16x8*)(As + Ra * 64 + ((ch ^ (Ra & 7)) << 3));
        bf[i] = *(const f16x8*)(Bs + Rb * 64 + ((ch ^ (Rb & 7)) << 3));
      }
#pragma unroll
      for (int i = 0; i < 4; i++)
#pragma unroll
        for (int j = 0; j < 4; j++)
          acc[i][j] = __builtin_amdgcn_mfma_f32_16x16x32_f16(af[i], bf[j], acc[i][j], 0, 0, 0);
    }
    __syncthreads();
  }
  const int crow0 = rowA0 + wr * 64, ccol0 = rowB0 + wc * 64;
#pragma unroll
  for (int i = 0; i < 4; i++)
#pragma unroll
    for (int j = 0; j < 4; j++)
#pragma unroll
      for (int r = 0; r < 4; r++) {
        int row = crow0 + i * 16 + (lane >> 4) * 4 + r;
        int col = ccol0 + j * 16 + (lane & 15);
        C[(size_t)row * n + col] = (_Float16)acc[i][j][r];
      }
}

// ---------------- fp16 MFMA node GEMM: C[M][Nn] = A[M][K] @ Bt[Nn][K]^T + epilogue ----
__global__ __launch_bounds__(256) void gemm_f16_node(const _Float16* __restrict__ A,
                                                     const _Float16* __restrict__ Bt,
                                                     const float* __restrict__ bias,
                                                     const float* __restrict__ add1,
                                                     const float* __restrict__ add2,
                                                     float* __restrict__ C,
                                                     _Float16* __restrict__ C16,
                                                     int M, int Nn, int K) {
  __shared__ _Float16 As[64 * 32];
  __shared__ _Float16 Bs[64 * 32];
  const int tid = threadIdx.x;
  const int lane = tid & 63, wave = tid >> 6;
  const int wr = wave >> 1, wc = wave & 1;
  const int m0 = blockIdx.y * 64, n0 = blockIdx.x * 64;
  const int fr = lane & 15, fk = (lane >> 4) * 8;
  const int gr = tid >> 2, gc = (tid & 3) * 8;
  f32x4 acc[2][2] = {};
  for (int k0 = 0; k0 < K; k0 += 32) {
    gload16(A + (size_t)(m0 + gr) * K + k0 + gc, As + tid * 8);
    gload16(Bt + (size_t)(n0 + gr) * K + k0 + gc, Bs + tid * 8);
    __syncthreads();
    f16x8 af[2], bf[2];
#pragma unroll
    for (int i = 0; i < 2; i++) {
      af[i] = *(const f16x8*)(As + (wr * 32 + i * 16 + fr) * 32 + fk);
      bf[i] = *(const f16x8*)(Bs + (wc * 32 + i * 16 + fr) * 32 + fk);
    }
#pragma unroll
    for (int i = 0; i < 2; i++)
#pragma unroll
      for (int j = 0; j < 2; j++)
        acc[i][j] = __builtin_amdgcn_mfma_f32_16x16x32_f16(af[i], bf[j], acc[i][j], 0, 0, 0);
    __syncthreads();
  }
  const int crow0 = m0 + wr * 32, ccol0 = n0 + wc * 32;
#pragma unroll
  for (int i = 0; i < 2; i++)
#pragma unroll
    for (int j = 0; j < 2; j++)
#pragma unroll
      for (int r = 0; r < 4; r++) {
        int row = crow0 + i * 16 + (lane >> 4) * 4 + r;
        int col = ccol0 + j * 16 + (lane & 15);
        float val = acc[i][j][r];
        if (bias) val += bias[col];
        if (add1) val += add1[(size_t)row * Nn + col];
        if (add2) val += add2[(size_t)row * Nn + col];
        C[(size_t)row * Nn + col] = val;
        if (C16) C16[(size_t)row * Nn + col] = (_Float16)val;
      }
}

// proj weight: [CATK][HID] f32 -> [HID][KPAD] f16
__global__ void wconv_proj_kernel(const float* __restrict__ W, _Float16* __restrict__ Wt) {
  int idx = blockIdx.x * 256 + threadIdx.x;
  if (idx >= HID * KPAD) return;
  int n = idx / KPAD, k = idx - n * KPAD;
  Wt[idx] = (k < CATK) ? (_Float16)W[(size_t)k * HID + n] : (_Float16)0.f;
}

// per-layer: Wq|Wk|Wv -> wt_qkv [768][256], Ws -> wt_s [256][256], bq|bk|bv -> bqkv[768]
__global__ void wconv_layer_kernel(const float* __restrict__ Wq, const float* __restrict__ Wk,
                                   const float* __restrict__ Wv, const float* __restrict__ Wsk,
                                   const float* __restrict__ bq, const float* __restrict__ bk,
                                   const float* __restrict__ bv,
                                   _Float16* __restrict__ wt_qkv, _Float16* __restrict__ wt_s,
                                   float* __restrict__ bqkv) {
  int idx = blockIdx.x * 256 + threadIdx.x;
  if (idx < 768) bqkv[idx] = (idx < 256) ? bq[idx] : (idx < 512 ? bk[idx - 256] : bv[idx - 512]);
  if (idx < 3 * HID * HID) {
    int n = idx >> 8, k = idx & 255;  // n in [0,768)
    const float* W = (n < 256) ? Wq : (n < 512 ? Wk : Wv);
    int nc = n & 255;
    wt_qkv[idx] = (_Float16)W[(size_t)k * HID + nc];
  } else {
    int j = idx - 3 * HID * HID;
    if (j < HID * HID) {
      int n = j >> 8, k = j & 255;
      wt_s[j] = (_Float16)Wsk[(size_t)k * HID + n];
    }
  }
}

// ---------------- diagonals ----------------
__global__ void diag_extract6_kernel(const _Float16* __restrict__ M1, const _Float16* __restrict__ M2,
                                     const _Float16* __restrict__ M3, const _Float16* __restrict__ M4,
                                     const _Float16* __restrict__ M8, const _Float16* __restrict__ M12,
                                     float* __restrict__ diags) {
  int i = blockIdx.x * 256 + threadIdx.x;
  if (i >= NN) return;
  size_t d = (size_t)i * (NN + 1);
  diags[0 * NN + i]  = (float)M1[d];
  diags[1 * NN + i]  = (float)M2[d];
  diags[2 * NN + i]  = (float)M3[d];
  diags[3 * NN + i]  = (float)M4[d];
  diags[7 * NN + i]  = (float)M8[d];
  diags[11 * NN + i] = (float)M12[d];
}

__device__ __forceinline__ float blk_reduce(float s, float* w4, int tid) {
  for (int d = 32; d; d >>= 1) s += __shfl_xor(s, d);
  if ((tid & 63) == 0) w4[tid >> 6] = s;
  __syncthreads();
  return w4[0] + w4[1] + w4[2] + w4[3];
}

__global__ void diag_prod3x1_kernel(const _Float16* __restrict__ X1, const _Float16* __restrict__ X2,
                                    const _Float16* __restrict__ X3, const _Float16* __restrict__ Yt,
                                    float* __restrict__ o1, float* __restrict__ o2,
                                    float* __restrict__ o3) {
  int row = blockIdx.x, tid = threadIdx.x;
  const f16x8* yp = (const f16x8*)(Yt + (size_t)row * NN);
  const f16x8* x1 = (const f16x8*)(X1 + (size_t)row * NN);
  const f16x8* x2 = (const f16x8*)(X2 + (size_t)row * NN);
  const f16x8* x3 = (const f16x8*)(X3 + (size_t)row * NN);
  float s1 = 0.f, s2 = 0.f, s3 = 0.f;
  for (int j = tid; j < NN / 8; j += 256) {
    f16x8 y = yp[j], a = x1[j], b = x2[j], c = x3[j];
#pragma unroll
    for (int r = 0; r < 8; r++) {
      float yv = (float)y[r];
      s1 += (float)a[r] * yv; s2 += (float)b[r] * yv; s3 += (float)c[r] * yv;
    }
  }
  __shared__ float w4[4];
  float t1 = blk_reduce(s1, w4, tid); __syncthreads();
  float t2 = blk_reduce(s2, w4, tid); __syncthreads();
  float t3 = blk_reduce(s3, w4, tid);
  if (tid == 0) { o1[row] = t1; o2[row] = t2; o3[row] = t3; }
}

__global__ void diag_prod1x3_kernel(const _Float16* __restrict__ X, const _Float16* __restrict__ Y1,
                                    const _Float16* __restrict__ Y2, const _Float16* __restrict__ Y3,
                                    float* __restrict__ o1, float* __restrict__ o2,
                                    float* __restrict__ o3) {
  int row = blockIdx.x, tid = threadIdx.x;
  const f16x8* xp = (const f16x8*)(X + (size_t)row * NN);
  const f16x8* y1 = (const f16x8*)(Y1 + (size_t)row * NN);
  const f16x8* y2 = (const f16x8*)(Y2 + (size_t)row * NN);
  const f16x8* y3 = (const f16x8*)(Y3 + (size_t)row * NN);
  float s1 = 0.f, s2 = 0.f, s3 = 0.f;
  for (int j = tid; j < NN / 8; j += 256) {
    f16x8 x = xp[j], a = y1[j], b = y2[j], c = y3[j];
#pragma unroll
    for (int r = 0; r < 8; r++) {
      float xv = (float)x[r];
      s1 += xv * (float)a[r]; s2 += xv * (float)b[r]; s3 += xv * (float)c[r];
    }
  }
  __shared__ float w4[4];
  float t1 = blk_reduce(s1, w4, tid); __syncthreads();
  float t2 = blk_reduce(s2, w4, tid); __syncthreads();
  float t3 = blk_reduce(s3, w4, tid);
  if (tid == 0) { o1[row] = t1; o2[row] = t2; o3[row] = t3; }
}

__global__ void diag_prod1x4_kernel(const _Float16* __restrict__ X, const _Float16* __restrict__ Y1,
                                    const _Float16* __restrict__ Y2, const _Float16* __restrict__ Y3,
                                    const _Float16* __restrict__ Y4,
                                    float* __restrict__ o1, float* __restrict__ o2,
                                    float* __restrict__ o3, float* __restrict__ o4) {
  int row = blockIdx.x, tid = threadIdx.x;
  const f16x8* xp = (const f16x8*)(X + (size_t)row * NN);
  const f16x8* y1 = (const f16x8*)(Y1 + (size_t)row * NN);
  const f16x8* y2 = (const f16x8*)(Y2 + (size_t)row * NN);
  const f16x8* y3 = (const f16x8*)(Y3 + (size_t)row * NN);
  const f16x8* y4 = (const f16x8*)(Y4 + (size_t)row * NN);
  float s1 = 0.f, s2 = 0.f, s3 = 0.f, s4 = 0.f;
  for (int j = tid; j < NN / 8; j += 256) {
    f16x8 x = xp[j], a = y1[j], b = y2[j], c = y3[j], d = y4[j];
#pragma unroll
    for (int r = 0; r < 8; r++) {
      float xv = (float)x[r];
      s1 += xv * (float)a[r]; s2 += xv * (float)b[r];
      s3 += xv * (float)c[r]; s4 += xv * (float)d[r];
    }
  }
  __shared__ float w4[4];
  float t1 = blk_reduce(s1, w4, tid); __syncthreads();
  float t2 = blk_reduce(s2, w4, tid); __syncthreads();
  float t3 = blk_reduce(s3, w4, tid); __syncthreads();
  float t4 = blk_reduce(s4, w4, tid);
  if (tid == 0) { o1[row] = t1; o2[row] = t2; o3[row] = t3; o4[row] = t4; }
}

__global__ void pe_kernel(const float* __restrict__ diags, const float* __restrict__ w,
                          const float* __restrict__ b, float* __restrict__ pe) {
  int idx = blockIdx.x * 256 + threadIdx.x;
  if (idx >= NN * 16) return;
  int i = idx >> 4, d = idx & 15;
  float s = b[d];
#pragma unroll
  for (int t = 0; t < 16; t++) s += diags[t * NN + i] * w[t * 16 + d];
  pe[idx] = s;
}

__global__ void concat16_kernel(const float* __restrict__ x, const float* __restrict__ pe,
                                _Float16* __restrict__ xc) {
  int idx = blockIdx.x * 256 + threadIdx.x;
  if (idx >= NN * KPAD) return;
  int i = idx / KPAD, c = idx - i * KPAD;
  float v = (c < INCH) ? x[(size_t)i * INCH + c]
                       : (c < CATK ? pe[(size_t)i * 16 + (c - INCH)] : 0.f);
  xc[idx] = (_Float16)v;
}

// ---------------- CSR ----------------
__global__ void csr_scan_kernel(const int* __restrict__ cnt, int* __restrict__ off) {
  int lane = threadIdx.x;  // single wave
  const int per = NN / 64;
  int s = 0;
  for (int i = 0; i < per; i++) s += cnt[lane * per + i];
  int run = s;
  for (int d = 1; d < 64; d <<= 1) {
    int t = __shfl_up(run, d);
    if (lane >= d) run += t;
  }
  int acc = run - s;
  for (int i = 0; i < per; i++) {
    off[lane * per + i] = acc;
    acc += cnt[lane * per + i];
  }
  if (lane == 63) off[NN] = acc;
}

__global__ void csr_fill_kernel(const int* __restrict__ sidx, const int* __restrict__ tidx,
                                const int* __restrict__ off, int* __restrict__ cur,
                                int* __restrict__ csrc) {
  int e = blockIdx.x * 256 + threadIdx.x;
  if (e >= NE) return;
  int t = tidx[e];
  int pos = atomicAdd(&cur[t], 1);
  csrc[off[t] + pos] = sidx[e];
}

// ---------------- fused attention: block per node, wave per head, online softmax ----
__global__ void attn_kernel(const int* __restrict__ off, const int* __restrict__ csrc,
                            const float* __restrict__ qkv, float* __restrict__ agg) {
  int node = blockIdx.x, tid = threadIdx.x;
  int h = tid >> 6, lane = tid & 63;
  int beg = off[node], end = off[node + 1];
  float q = qkv[(size_t)node * 768 + h * 64 + lane];
  float m = -INFINITY, denom = 0.f, acc = 0.f;
  for (int i = beg; i < end; ++i) {
    int s = csrc[i];
    const float* row = qkv + (size_t)s * 768;
    float p = q * row[256 + h * 64 + lane];
    for (int d = 32; d; d >>= 1) p += __shfl_xor(p, d);
    float sc = p * 0.125f;
    float mn = fmaxf(m, sc);
    float scale = expf(m - mn);   // m=-inf first iter -> 0
    float e = expf(sc - mn);
    float vv = row[512 + h * 64 + lane];
    denom = denom * scale + e;
    acc = acc * scale + e * vv;
    m = mn;
  }
  agg[(size_t)node * HID + h * 64 + lane] = acc / fmaxf(denom, 1e-16f);
}

__global__ void ln_relu_kernel(const float* __restrict__ z, const float* __restrict__ g,
                               const float* __restrict__ b, float* __restrict__ out,
                               _Float16* __restrict__ out16) {
  int row = blockIdx.x, tid = threadIdx.x;
  float v = z[(size_t)row * HID + tid];
  float s = v;
  for (int d = 32; d; d >>= 1) s += __shfl_xor(s, d);
  __shared__ float w4[4], w4b[4];
  int wv = tid >> 6, lane = tid & 63;
  if (lane == 0) w4[wv] = s;
  __syncthreads();
  float mu = (w4[0] + w4[1] + w4[2] + w4[3]) * (1.f / HID);
  float dv = v - mu;
  float q = dv * dv;
  for (int d = 32; d; d >>= 1) q += __shfl_xor(q, d);
  if (lane == 0) w4b[wv] = q;
  __syncthreads();
  float var = (w4b[0] + w4b[1] + w4b[2] + w4b[3]) * (1.f / HID);
  float y = dv * (1.f / sqrtf(var + 1e-5f)) * g[tid] + b[tid];
  y = fmaxf(y, 0.f);
  out[(size_t)row * HID + tid] = y;
  out16[(size_t)row * HID + tid] = (_Float16)y;
}

__global__ void decode_kernel(const float* __restrict__ h, const int* __restrict__ src,
                              const int* __restrict__ dst, float* __restrict__ out) {
  int wv = threadIdx.x >> 6, lane = threadIdx.x & 63;
  int p = blockIdx.x * 4 + wv;
  if (p >= NP) return;
  const float4* a = (const float4*)(h + (size_t)src[p] * HID);
  const float4* b = (const float4*)(h + (size_t)dst[p] * HID);
  float4 x = a[lane], y = b[lane];
  float s = x.x * y.x + x.y * y.y + x.z * y.z + x.w * y.w;
  for (int d = 32; d; d >>= 1) s += __shfl_xor(s, d);
  if (lane == 0) out[p] = 1.f / (1.f + expf(-s));
}

// ---------------- host launch ----------------
extern "C" void kernel_launch(void* const* d_in, const int* in_sizes, int n_in,
                              void* d_out, int out_size, void* d_ws, size_t ws_size,
                              hipStream_t stream) {
  const float* x      = (const float*)d_in[0];
  const int*   ei     = (const int*)d_in[1];
  const int*   src    = (const int*)d_in[2];
  const int*   dst    = (const int*)d_in[3];
  const float* rwse_w = (const float*)d_in[4];
  const float* rwse_b = (const float*)d_in[5];
  const float* proj_w = (const float*)d_in[6];
  const float* proj_b = (const float*)d_in[7];
  const float* Wq     = (const float*)d_in[8];
  const float* bq     = (const float*)d_in[9];
  const float* Wk     = (const float*)d_in[10];
  const float* bk     = (const float*)d_in[11];
  const float* Wv     = (const float*)d_in[12];
  const float* bv     = (const float*)d_in[13];
  const float* Wsk    = (const float*)d_in[14];
  const float* bs     = (const float*)d_in[15];
  const float* ln_g   = (const float*)d_in[16];
  const float* ln_b   = (const float*)d_in[17];
  float* out = (float*)d_out;

  const size_t MAT = (size_t)NN * NN * sizeof(_Float16);
  char* base = (char*)d_ws;
  _Float16* rw   = (_Float16*)(base + 0 * MAT);
  _Float16* rwT  = (_Float16*)(base + 1 * MAT);
  _Float16* rw2  = (_Float16*)(base + 2 * MAT);
  _Float16* rw2T = (_Float16*)(base + 3 * MAT);
  _Float16* rw3  = (_Float16*)(base + 4 * MAT);
  _Float16* rw3T = (_Float16*)(base + 5 * MAT);
  _Float16* rw4  = (_Float16*)(base + 6 * MAT);
  _Float16* rw4T = (_Float16*)(base + 7 * MAT);
  _Float16* rw8  = (_Float16*)(base + 8 * MAT);
  _Float16* rw12 = (_Float16*)(base + 9 * MAT);
  float* adj = (float*)(base + 8 * MAT);  // overlaps rw8/rw12: adj dead before they're written
  char* sm = base + 10 * MAT;
  float* diags  = (float*)sm; sm += (size_t)16 * NN * 4;
  float* pe     = (float*)sm; sm += (size_t)NN * 16 * 4;
  float* hbuf   = (float*)sm; sm += (size_t)NN * HID * 4;
  float* qkv    = (float*)sm; sm += (size_t)NN * 768 * 4;   // q|k|v per node
  float* aggb   = (float*)sm; sm += (size_t)NN * HID * 4;
  float* zb     = (float*)sm; sm += (size_t)NN * HID * 4;
  int* cnt = (int*)sm; sm += 12288;
  int* cur = (int*)sm; sm += 12288;
  int* off = (int*)sm; sm += 16384;
  int* csrc = (int*)sm; sm += (size_t)NE * 4;
  _Float16* h16  = (_Float16*)sm; sm += (size_t)NN * HID * 2;
  _Float16* xc16 = (_Float16*)sm; sm += (size_t)NN * KPAD * 2;
  _Float16* wt_proj = (_Float16*)sm; sm += (size_t)HID * KPAD * 2;
  _Float16* wt_qkv[2]; _Float16* wt_s[2]; float* bqkv[2];
  for (int l = 0; l < 2; ++l) {
    wt_qkv[l] = (_Float16*)sm; sm += (size_t)3 * HID * HID * 2;
    wt_s[l]   = (_Float16*)sm; sm += (size_t)HID * HID * 2;
    bqkv[l]   = (float*)sm;    sm += 768 * 4;
  }
  (void)in_sizes; (void)n_in; (void)out_size; (void)ws_size;

  const dim3 B256(256);
  const dim3 gT(NN / 64, NN / 64);
  const int  gG = (NN / 128) * (NN / 128);   // 576, 1D
  const dim3 gQKV(768 / 64, NN / 64);
  const dim3 gS(HID / 64, NN / 64);

  // --- weight prep ---
  wconv_proj_kernel<<<(HID * KPAD + 255) / 256, B256, 0, stream>>>(proj_w, wt_proj);
  for (int l = 0; l < 2; ++l)
    wconv_layer_kernel<<<(4 * HID * HID + 255) / 256, B256, 0, stream>>>(
        Wq + (size_t)l * HID * HID, Wk + (size_t)l * HID * HID, Wv + (size_t)l * HID * HID,
        Wsk + (size_t)l * HID * HID, bq + l * HID, bk + l * HID, bv + l * HID,
        wt_qkv[l], wt_s[l], bqkv[l]);

  // --- adjacency + in-degree ---
  hipMemsetAsync(adj, 0, (size_t)NN * NN * 4, stream);
  hipMemsetAsync(cnt, 0, 12288, stream);
  hipMemsetAsync(cur, 0, 12288, stream);
  edges_kernel<<<(NE + 255) / 256, B256, 0, stream>>>(ei, adj, cnt);
  rownorm_kernel<<<NN, B256, 0, stream>>>(adj, rw);
  csr_scan_kernel<<<1, 64, 0, stream>>>(cnt, off);
  csr_fill_kernel<<<(NE + 255) / 256, B256, 0, stream>>>(ei, ei + NE, off, cur, csrc);

  // --- RWSE power chain ---
  transpose_f16_kernel<<<gT, B256, 0, stream>>>((const unsigned short*)rw, (unsigned short*)rwT);
  gemm_f16_nt<<<gG, B256, 0, stream>>>(rw, rwT, rw2, NN);
  transpose_f16_kernel<<<gT, B256, 0, stream>>>((const unsigned short*)rw2, (unsigned short*)rw2T);
  gemm_f16_nt<<<gG, B256, 0, stream>>>(rw2, rwT, rw3, NN);
  transpose_f16_kernel<<<gT, B256, 0, stream>>>((const unsigned short*)rw3, (unsigned short*)rw3T);
  gemm_f16_nt<<<gG, B256, 0, stream>>>(rw3, rwT, rw4, NN);
  transpose_f16_kernel<<<gT, B256, 0, stream>>>((const unsigned short*)rw4, (unsigned short*)rw4T);
  gemm_f16_nt<<<gG, B256, 0, stream>>>(rw4, rw4T, rw8, NN);
  gemm_f16_nt<<<gG, B256, 0, stream>>>(rw8, rw4T, rw12, NN);

  diag_extract6_kernel<<<NN / 256, B256, 0, stream>>>(rw, rw2, rw3, rw4, rw8, rw12, diags);
  diag_prod3x1_kernel<<<NN, B256, 0, stream>>>(rw, rw2, rw3, rw4T,
                                               diags + 4 * NN, diags + 5 * NN, diags + 6 * NN);
  diag_prod1x3_kernel<<<NN, B256, 0, stream>>>(rw8, rwT, rw2T, rw3T,
                                               diags + 8 * NN, diags + 9 * NN, diags + 10 * NN);
  diag_prod1x4_kernel<<<NN, B256, 0, stream>>>(rw12, rwT, rw2T, rw3T, rw4T,
                                               diags + 12 * NN, diags + 13 * NN,
                                               diags + 14 * NN, diags + 15 * NN);

  pe_kernel<<<(NN * 16) / 256, B256, 0, stream>>>(diags, rwse_w, rwse_b, pe);
  concat16_kernel<<<(NN * KPAD + 255) / 256, B256, 0, stream>>>(x, pe, xc16);
  gemm_f16_node<<<gS, B256, 0, stream>>>(xc16, wt_proj, proj_b, nullptr, nullptr,
                                         hbuf, h16, NN, HID, KPAD);

  // --- transformer layers ---
  for (int l = 0; l < 2; ++l) {
    gemm_f16_node<<<gQKV, B256, 0, stream>>>(h16, wt_qkv[l], bqkv[l], nullptr, nullptr,
                                             qkv, nullptr, NN, 768, HID);
    attn_kernel<<<NN, B256, 0, stream>>>(off, csrc, qkv, aggb);
    gemm_f16_node<<<gS, B256, 0, stream>>>(h16, wt_s[l], bs + l * HID, hbuf, aggb,
                                           zb, nullptr, NN, HID, HID);
    ln_relu_kernel<<<NN, B256, 0, stream>>>(zb, ln_g + l * HID, ln_b + l * HID, hbuf, h16);
  }

  decode_kernel<<<NP / 4, B256, 0, stream>>>(hbuf, src, dst, out);
}